// Round 12
// baseline (118.192 us; speedup 1.0000x reference)
//
#include <hip/hip_runtime.h>

#define DEVI __device__ __forceinline__

typedef __attribute__((ext_vector_type(8))) short short8;
typedef __attribute__((ext_vector_type(4))) float f32x4;
typedef __attribute__((ext_vector_type(16))) float f32x16;

DEVI unsigned short f32_to_bf16(float f) {
  unsigned int u = __float_as_uint(f);
  u += 0x7fffu + ((u >> 16) & 1u);
  return (unsigned short)(u >> 16);
}
DEVI float bf16_to_f32(unsigned short h) {
  return __uint_as_float(((unsigned int)h) << 16);
}

DEVI void gld_lds16(const void* g, void* l) {
  __builtin_amdgcn_global_load_lds(
      (__attribute__((address_space(1))) void*)(g),
      (__attribute__((address_space(3))) void*)(l), 16, 0, 0);
}

// ---------------- plain cast: fp32 -> bf16 (for GEMM1 A-side) ----------------
__global__ void k_cast_bf16(const float* __restrict__ in, unsigned short* __restrict__ out,
                            int total8) {
  int i = blockIdx.x * blockDim.x + threadIdx.x;
  if (i >= total8) return;
  const float* src = in + i * 8;
  short8 v;
#pragma unroll
  for (int j = 0; j < 8; ++j) v[j] = (short)f32_to_bf16(src[j]);
  *(short8*)&out[(size_t)i * 8] = v;
}

// ---------------- plain transpose-cast: W [K][N] fp32 -> Wt [N][K] bf16 ------
__global__ __launch_bounds__(256) void k_cast_Bt(const float* __restrict__ W,
                                                 unsigned short* __restrict__ Wt,
                                                 int K, int N) {
  int kt = blockIdx.x, nt = blockIdx.y;
  __shared__ float t[32][33];
  int tid = threadIdx.x;
#pragma unroll
  for (int p = 0; p < 4; ++p) {
    int idx = tid + p * 256;
    int rr = idx >> 5, cc = idx & 31;
    t[rr][cc] = W[(size_t)(kt * 32 + rr) * N + nt * 32 + cc];
  }
  __syncthreads();
#pragma unroll
  for (int p = 0; p < 4; ++p) {
    int idx = tid + p * 256;
    int rn = idx >> 5, ck = idx & 31;
    Wt[(size_t)(nt * 32 + rn) * K + kt * 32 + ck] = f32_to_bf16(t[ck][rn]);
  }
}

// ---------------- GEMM1: 128x128 tile, QKV scatter epilogue ----------------
// Q section is pre-scaled by 0.125*log2(e) so attn's exp2 takes raw MFMA output.
__global__ __launch_bounds__(256) void k_gemm_qkv(const unsigned short* __restrict__ A,
                                                  const unsigned short* __restrict__ Bt,
                                                  const float* __restrict__ bias,
                                                  int M, int N, int K,
                                                  unsigned short* __restrict__ Qo,
                                                  unsigned short* __restrict__ Ko,
                                                  unsigned short* __restrict__ Vo) {
  __shared__ __align__(16) unsigned short As[128 * 32];
  __shared__ __align__(16) unsigned short Bs[128 * 32];
  int tid = threadIdx.x;
  int tm = blockIdx.x, tn = blockIdx.y;
  int lane = tid & 63, wid = tid >> 6;
  int wr = wid >> 1, wc = wid & 1;
  int g = lane >> 4, lr = lane & 15;
  f32x4 acc[4][4] = {};
  int srow = tid >> 2;
  int scol = (tid & 3) * 8;
  const unsigned short* Ab = A + (size_t)tm * 128 * K;
  const unsigned short* Bb = Bt + (size_t)tn * 128 * K;
  for (int k0 = 0; k0 < K; k0 += 32) {
    gld_lds16(Ab + (size_t)srow * K + k0 + scol, &As[srow * 32 + scol]);
    gld_lds16(Ab + (size_t)(srow + 64) * K + k0 + scol, &As[(srow + 64) * 32 + scol]);
    gld_lds16(Bb + (size_t)srow * K + k0 + scol, &Bs[srow * 32 + scol]);
    gld_lds16(Bb + (size_t)(srow + 64) * K + k0 + scol, &Bs[(srow + 64) * 32 + scol]);
    __syncthreads();
    short8 a[4], b[4];
#pragma unroll
    for (int m = 0; m < 4; ++m)
      a[m] = *(const short8*)&As[(wr * 64 + m * 16 + lr) * 32 + g * 8];
#pragma unroll
    for (int n = 0; n < 4; ++n)
      b[n] = *(const short8*)&Bs[(wc * 64 + n * 16 + lr) * 32 + g * 8];
#pragma unroll
    for (int m = 0; m < 4; ++m)
#pragma unroll
      for (int n = 0; n < 4; ++n)
        acc[m][n] = __builtin_amdgcn_mfma_f32_16x16x32_bf16(a[m], b[n], acc[m][n], 0, 0, 0);
    __syncthreads();
  }
  const float QSCALE = 0.125f * 1.4426950408889634f;
#pragma unroll
  for (int m = 0; m < 4; ++m) {
#pragma unroll
    for (int n = 0; n < 4; ++n) {
      int col = tn * 128 + wc * 64 + n * 16 + lr;
      float bv = bias[col];
      int sec = (col >= 1536) ? 2 : ((col >= 768) ? 1 : 0);
      int c = col - sec * 768;
      int hh = c >> 6, d = c & 63;
#pragma unroll
      for (int j = 0; j < 4; ++j) {
        int row = tm * 128 + wr * 64 + m * 16 + g * 4 + j;
        int bb = row >> 11, nn = row & 2047;
        size_t dst = (((size_t)(bb * 12 + hh) << 11) + nn) * 64 + d;
        float outv = acc[m][n][j] + bv;
        if (sec == 0) {
          Qo[dst] = f32_to_bf16(outv * QSCALE);
        } else if (sec == 1) {
          Ko[dst] = f32_to_bf16(outv);
        } else {
          Vo[dst] = f32_to_bf16(outv);
        }
      }
    }
  }
}

// ---------------- GEMM2: 64x64 tile, grid (64,12)=768 blocks ----------------
__global__ __launch_bounds__(256) void k_gemm2(const unsigned short* __restrict__ A,
                                               const unsigned short* __restrict__ Bt,
                                               const float* __restrict__ bias,
                                               float* __restrict__ C,
                                               int M, int N, int K) {
  __shared__ __align__(16) unsigned short As[64 * 32];
  __shared__ __align__(16) unsigned short Bs[64 * 32];
  int tid = threadIdx.x;
  int tm = blockIdx.x, tn = blockIdx.y;
  int lane = tid & 63, wid = tid >> 6;
  int wr = wid >> 1, wc = wid & 1;
  int g = lane >> 4, lr = lane & 15;
  f32x4 acc[2][2] = {};
  int srow = tid >> 2;
  int scol = (tid & 3) * 8;
  const unsigned short* Ab = A + (size_t)tm * 64 * K;
  const unsigned short* Bb = Bt + (size_t)tn * 64 * K;
  for (int k0 = 0; k0 < K; k0 += 32) {
    gld_lds16(Ab + (size_t)srow * K + k0 + scol, &As[srow * 32 + scol]);
    gld_lds16(Bb + (size_t)srow * K + k0 + scol, &Bs[srow * 32 + scol]);
    __syncthreads();
    short8 a[2], b[2];
#pragma unroll
    for (int m = 0; m < 2; ++m)
      a[m] = *(const short8*)&As[(wr * 32 + m * 16 + lr) * 32 + g * 8];
#pragma unroll
    for (int n = 0; n < 2; ++n)
      b[n] = *(const short8*)&Bs[(wc * 32 + n * 16 + lr) * 32 + g * 8];
#pragma unroll
    for (int m = 0; m < 2; ++m)
#pragma unroll
      for (int n = 0; n < 2; ++n)
        acc[m][n] = __builtin_amdgcn_mfma_f32_16x16x32_bf16(a[m], b[n], acc[m][n], 0, 0, 0);
    __syncthreads();
  }
#pragma unroll
  for (int m = 0; m < 2; ++m) {
#pragma unroll
    for (int n = 0; n < 2; ++n) {
      int col = tn * 64 + wc * 32 + n * 16 + lr;
      float bv = bias[col];
#pragma unroll
      for (int j = 0; j < 4; ++j) {
        int row = tm * 64 + wr * 32 + m * 16 + g * 4 + j;
        C[(size_t)row * N + col] = acc[m][n][j] + bv;
      }
    }
  }
}

// V transpose: Vc [24][2048][64] -> Vt [24][64][2048]
__global__ __launch_bounds__(256) void k_v_transpose(const unsigned short* __restrict__ Vc,
                                                     unsigned short* __restrict__ Vt) {
  int bh = blockIdx.x;  // 24
  int nt = blockIdx.y;  // 32
  __shared__ unsigned short s[64][65];
  int tid = threadIdx.x;
  int r = tid >> 2;
#pragma unroll
  for (int p = 0; p < 2; ++p) {
    int c = (tid & 3) + p * 4;
    short8 v = *(const short8*)&Vc[((size_t)(bh * 2048 + nt * 64 + r)) * 64 + c * 8];
#pragma unroll
    for (int ii = 0; ii < 8; ++ii) s[r][c * 8 + ii] = (unsigned short)v[ii];
  }
  __syncthreads();
  int d = tid >> 2;
#pragma unroll
  for (int p = 0; p < 2; ++p) {
    int c = (tid & 3) + p * 4;
    short8 w;
#pragma unroll
    for (int ii = 0; ii < 8; ++ii) w[ii] = (short)s[c * 8 + ii][d];
    *(short8*)&Vt[((size_t)bh * 64 + d) * 2048 + nt * 64 + c * 8] = w;
  }
}

// ---------------- flash attention: 32x32 MFMA, in-register P ----------------
// 2 waves x 32 q = 64 q/block, KV tile 64, dbuf. Grid (24,32)=768. LDS 32KB.
// Swapped QK at 32x32 => P^T col = q = lane&31 (lane-resident); cvt_pk +
// v_permlane32_swap_b32 (vdst = LOW-k word: exchanges vdst.hi <-> vsrc.lo)
// converts C-layout (k=(r&3)+8(r>>2)+4hi) into PV A-layout (k=hi*8+e).

#define ATTN_STAGE(KSB, VSB, T)                                                          \
  {                                                                                      \
    int kv0 = (T) * 64;                                                                  \
    _Pragma("unroll") for (int it = 0; it < 4; ++it) {                                   \
      int L = tid + it * 128;                                                            \
      int rw = L >> 3, s7 = L & 7;                                                       \
      gld_lds16(Kb + (size_t)(khead + kv0 + rw) * 64 + ((s7 ^ (rw & 7)) * 8),            \
                &KSB[L * 8]);                                                            \
      gld_lds16(Vt + (size_t)(vhead + rw) * 2048 + kv0 + ((s7 ^ (rw & 7)) * 8),          \
                &VSB[L * 8]);                                                            \
    }                                                                                    \
  }

// Build two PV A-frags (ks = KS0, KS0+1) from one 32x32 P accumulator S.
// w_low = cvtpk(S[b],S[b+1]) (vdst), w_high = cvtpk(S[b+4],S[b+5]) (vsrc):
// swap exchanges w_low.hi <-> w_high.lo.
#define BUILD_PA(S, KS0)                                                                 \
  {                                                                                      \
    unsigned int b0, a0, e0, c0;                                                         \
    asm("v_cvt_pk_bf16_f32 %0, %1, %2" : "=v"(b0) : "v"(S[0]), "v"(S[1]));               \
    asm("v_cvt_pk_bf16_f32 %0, %1, %2" : "=v"(a0) : "v"(S[4]), "v"(S[5]));               \
    asm("v_permlane32_swap_b32 %0, %1" : "+v"(b0), "+v"(a0));                            \
    asm("v_cvt_pk_bf16_f32 %0, %1, %2" : "=v"(e0) : "v"(S[2]), "v"(S[3]));               \
    asm("v_cvt_pk_bf16_f32 %0, %1, %2" : "=v"(c0) : "v"(S[6]), "v"(S[7]));               \
    asm("v_permlane32_swap_b32 %0, %1" : "+v"(e0), "+v"(c0));                            \
    paw[KS0][0] = b0; paw[KS0][1] = e0; paw[KS0][2] = a0; paw[KS0][3] = c0;              \
    unsigned int b1, a1, e1, c1;                                                         \
    asm("v_cvt_pk_bf16_f32 %0, %1, %2" : "=v"(b1) : "v"(S[8]), "v"(S[9]));               \
    asm("v_cvt_pk_bf16_f32 %0, %1, %2" : "=v"(a1) : "v"(S[12]), "v"(S[13]));             \
    asm("v_permlane32_swap_b32 %0, %1" : "+v"(b1), "+v"(a1));                            \
    asm("v_cvt_pk_bf16_f32 %0, %1, %2" : "=v"(e1) : "v"(S[10]), "v"(S[11]));             \
    asm("v_cvt_pk_bf16_f32 %0, %1, %2" : "=v"(c1) : "v"(S[14]), "v"(S[15]));             \
    asm("v_permlane32_swap_b32 %0, %1" : "+v"(e1), "+v"(c1));                            \
    paw[KS0 + 1][0] = b1; paw[KS0 + 1][1] = e1; paw[KS0 + 1][2] = a1; paw[KS0 + 1][3] = c1; \
  }

#define PROC_TILE(KSB, VSB)                                                              \
  {                                                                                      \
    f32x16 sa = {}, sb = {};                                                             \
    __builtin_amdgcn_s_setprio(1);                                                       \
    _Pragma("unroll") for (int ds = 0; ds < 4; ++ds) {                                   \
      short8 kf0 = *(const short8*)&KSB[ln31 * 64 + (((ds * 2 + hi) ^ ln7) * 8)];        \
      short8 kf1 = *(const short8*)&KSB[(32 + ln31) * 64 + (((ds * 2 + hi) ^ ln7) * 8)]; \
      sa = __builtin_amdgcn_mfma_f32_32x32x16_bf16(kf0, qf[ds], sa, 0, 0, 0);            \
      sb = __builtin_amdgcn_mfma_f32_32x32x16_bf16(kf1, qf[ds], sb, 0, 0, 0);            \
    }                                                                                    \
    __builtin_amdgcn_s_setprio(0);                                                       \
    _Pragma("unroll") for (int i = 0; i < 16; ++i) {                                     \
      float pv = exp2f(sa[i]);                                                           \
      sa[i] = pv;                                                                        \
      lrun += pv;                                                                        \
    }                                                                                    \
    _Pragma("unroll") for (int i = 0; i < 16; ++i) {                                     \
      float pv = exp2f(sb[i]);                                                           \
      sb[i] = pv;                                                                        \
      lrun += pv;                                                                        \
    }                                                                                    \
    unsigned int paw[4][4];                                                              \
    BUILD_PA(sa, 0)                                                                      \
    BUILD_PA(sb, 2)                                                                      \
    __builtin_amdgcn_s_setprio(1);                                                       \
    _Pragma("unroll") for (int ks = 0; ks < 4; ++ks) {                                   \
      union {                                                                            \
        unsigned int u[4];                                                               \
        short8 s8;                                                                       \
      } pu;                                                                              \
      pu.u[0] = paw[ks][0];                                                              \
      pu.u[1] = paw[ks][1];                                                              \
      pu.u[2] = paw[ks][2];                                                              \
      pu.u[3] = paw[ks][3];                                                              \
      short8 vb0 = *(const short8*)&VSB[ln31 * 64 + (((ks * 2 + hi) ^ ln7) * 8)];        \
      short8 vb1 = *(const short8*)&VSB[(32 + ln31) * 64 + (((ks * 2 + hi) ^ ln7) * 8)]; \
      oacc0 = __builtin_amdgcn_mfma_f32_32x32x16_bf16(pu.s8, vb0, oacc0, 0, 0, 0);       \
      oacc1 = __builtin_amdgcn_mfma_f32_32x32x16_bf16(pu.s8, vb1, oacc1, 0, 0, 0);       \
    }                                                                                    \
    __builtin_amdgcn_s_setprio(0);                                                       \
  }

__global__ __launch_bounds__(128, 3) void k_attn(const unsigned short* __restrict__ Qb,
                                                 const unsigned short* __restrict__ Kb,
                                                 const unsigned short* __restrict__ Vt,
                                                 unsigned short* __restrict__ Xh) {
  int bh = blockIdx.x;  // 24
  int qb = blockIdx.y;  // 32
  int b = bh / 12, h = bh - b * 12;
  __shared__ __align__(16) unsigned short Ks0[64 * 64], Ks1[64 * 64];
  __shared__ __align__(16) unsigned short Vs0[64 * 64], Vs1[64 * 64];
  int tid = threadIdx.x;
  int wid = tid >> 6, lane = tid & 63;
  int ln31 = lane & 31, hi = lane >> 5, ln7 = lane & 7;
  int khead = bh * 2048;
  int vhead = bh * 64;
  int q0 = qb * 64 + wid * 32;

  // Q B-operand frags: lane holds Q[q0+ln31][ds*16 + hi*8 + e]
  short8 qf[4];
#pragma unroll
  for (int ds = 0; ds < 4; ++ds)
    qf[ds] = *(const short8*)&Qb[(size_t)(khead + q0 + ln31) * 64 + ds * 16 + hi * 8];

  float lrun = 0.f;
  f32x16 oacc0 = {}, oacc1 = {};

  ATTN_STAGE(Ks0, Vs0, 0);
  __syncthreads();
#pragma unroll 1
  for (int tt = 0; tt < 16; ++tt) {
    ATTN_STAGE(Ks1, Vs1, 2 * tt + 1);
    PROC_TILE(Ks0, Vs0);
    __syncthreads();
    if (tt < 15) ATTN_STAGE(Ks0, Vs0, 2 * tt + 2);
    PROC_TILE(Ks1, Vs1);
    __syncthreads();
  }

  // denom: lane's lrun covers its hi-half's k rows; combine halves (same q).
  lrun += __shfl_xor(lrun, 32, 64);
  float linv = 1.0f / lrun;
#pragma unroll
  for (int r = 0; r < 16; ++r) {
    int qrow = (r & 3) + 8 * (r >> 2) + 4 * hi;
    float lf = __shfl(linv, qrow, 64);
    int grow = b * 2048 + q0 + qrow;
    int colb = h * 64 + ln31;
    Xh[(size_t)grow * 768 + colb] = f32_to_bf16(oacc0[r] * lf);
    Xh[(size_t)grow * 768 + colb + 32] = f32_to_bf16(oacc1[r] * lf);
  }
}

// ---------------- launch ----------------
extern "C" void kernel_launch(void* const* d_in, const int* in_sizes, int n_in,
                              void* d_out, int out_size, void* d_ws, size_t ws_size,
                              hipStream_t stream) {
  const float* x = (const float*)d_in[0];      // [2,2048,768]
  const float* W_qkv = (const float*)d_in[1];  // [768,2304]
  const float* b_qkv = (const float*)d_in[2];  // [2304]
  const float* W_out = (const float*)d_in[3];  // [768,768]
  const float* b_out = (const float*)d_in[4];  // [768]
  float* out = (float*)d_out;                  // [4096,768]
  char* ws = (char*)d_ws;

  unsigned short* Xh = (unsigned short*)(ws + 0);           // 4096x768 bf16 (attn out H)
  unsigned short* Xb = (unsigned short*)(ws + 18874368);    // 4096x768 bf16 (x cast)
  unsigned short* Wq_t = (unsigned short*)(ws + 25165824);  // 2304x768 bf16
  unsigned short* Wo_t = (unsigned short*)(ws + 28704768);  // 768x768 bf16
  unsigned short* Qb = (unsigned short*)(ws + 32243712);    // 24x2048x64 (pre-scaled)
  unsigned short* Kb = (unsigned short*)(ws + 38535168);    // 24x2048x64
  unsigned short* Vc = (unsigned short*)(ws + 44826624);    // 24x2048x64
  unsigned short* Vt = (unsigned short*)(ws + 51118080);    // 24x64x2048

  k_cast_bf16<<<(4096 * 768 / 8 + 255) / 256, 256, 0, stream>>>(x, Xb, 4096 * 768 / 8);
  k_cast_Bt<<<dim3(24, 72), 256, 0, stream>>>(W_qkv, Wq_t, 768, 2304);
  k_cast_Bt<<<dim3(24, 24), 256, 0, stream>>>(W_out, Wo_t, 768, 768);
  k_gemm_qkv<<<dim3(32, 18), 256, 0, stream>>>(Xb, Wq_t, b_qkv, 4096, 2304, 768, Qb, Kb, Vc);
  k_v_transpose<<<dim3(24, 32), 256, 0, stream>>>(Vc, Vt);
  k_attn<<<dim3(24, 32), 128, 0, stream>>>(Qb, Kb, Vt, Xh);
  k_gemm2<<<dim3(64, 12), 256, 0, stream>>>(Xh, Wo_t, b_out, out, 4096, 768, 768);
}

// Round 13
// 105.947 us; speedup vs baseline: 1.1156x; 1.1156x over previous
//
#include <hip/hip_runtime.h>

#define DEVI __device__ __forceinline__

typedef __attribute__((ext_vector_type(8))) short short8;
typedef __attribute__((ext_vector_type(4))) float f32x4;
typedef __attribute__((ext_vector_type(16))) float f32x16;

DEVI unsigned short f32_to_bf16(float f) {
  unsigned int u = __float_as_uint(f);
  u += 0x7fffu + ((u >> 16) & 1u);
  return (unsigned short)(u >> 16);
}
DEVI float bf16_to_f32(unsigned short h) {
  return __uint_as_float(((unsigned int)h) << 16);
}

DEVI void gld_lds16(const void* g, void* l) {
  __builtin_amdgcn_global_load_lds(
      (__attribute__((address_space(1))) void*)(g),
      (__attribute__((address_space(3))) void*)(l), 16, 0, 0);
}

// ---------------- plain cast: fp32 -> bf16 (for GEMM1 A-side) ----------------
__global__ void k_cast_bf16(const float* __restrict__ in, unsigned short* __restrict__ out,
                            int total8) {
  int i = blockIdx.x * blockDim.x + threadIdx.x;
  if (i >= total8) return;
  const float* src = in + i * 8;
  short8 v;
#pragma unroll
  for (int j = 0; j < 8; ++j) v[j] = (short)f32_to_bf16(src[j]);
  *(short8*)&out[(size_t)i * 8] = v;
}

// ---------------- plain transpose-cast: W [K][N] fp32 -> Wt [N][K] bf16 ------
__global__ __launch_bounds__(256) void k_cast_Bt(const float* __restrict__ W,
                                                 unsigned short* __restrict__ Wt,
                                                 int K, int N) {
  int kt = blockIdx.x, nt = blockIdx.y;
  __shared__ float t[32][33];
  int tid = threadIdx.x;
#pragma unroll
  for (int p = 0; p < 4; ++p) {
    int idx = tid + p * 256;
    int rr = idx >> 5, cc = idx & 31;
    t[rr][cc] = W[(size_t)(kt * 32 + rr) * N + nt * 32 + cc];
  }
  __syncthreads();
#pragma unroll
  for (int p = 0; p < 4; ++p) {
    int idx = tid + p * 256;
    int rn = idx >> 5, ck = idx & 31;
    Wt[(size_t)(nt * 32 + rn) * K + kt * 32 + ck] = f32_to_bf16(t[ck][rn]);
  }
}

// ---------------- GEMM1: 128x128 tile, QKV scatter epilogue ----------------
// Q section is pre-scaled by 0.125*log2(e) so attn's exp2 takes raw MFMA output.
__global__ __launch_bounds__(256) void k_gemm_qkv(const unsigned short* __restrict__ A,
                                                  const unsigned short* __restrict__ Bt,
                                                  const float* __restrict__ bias,
                                                  int M, int N, int K,
                                                  unsigned short* __restrict__ Qo,
                                                  unsigned short* __restrict__ Ko,
                                                  unsigned short* __restrict__ Vo) {
  __shared__ __align__(16) unsigned short As[128 * 32];
  __shared__ __align__(16) unsigned short Bs[128 * 32];
  int tid = threadIdx.x;
  int tm = blockIdx.x, tn = blockIdx.y;
  int lane = tid & 63, wid = tid >> 6;
  int wr = wid >> 1, wc = wid & 1;
  int g = lane >> 4, lr = lane & 15;
  f32x4 acc[4][4] = {};
  int srow = tid >> 2;
  int scol = (tid & 3) * 8;
  const unsigned short* Ab = A + (size_t)tm * 128 * K;
  const unsigned short* Bb = Bt + (size_t)tn * 128 * K;
  for (int k0 = 0; k0 < K; k0 += 32) {
    gld_lds16(Ab + (size_t)srow * K + k0 + scol, &As[srow * 32 + scol]);
    gld_lds16(Ab + (size_t)(srow + 64) * K + k0 + scol, &As[(srow + 64) * 32 + scol]);
    gld_lds16(Bb + (size_t)srow * K + k0 + scol, &Bs[srow * 32 + scol]);
    gld_lds16(Bb + (size_t)(srow + 64) * K + k0 + scol, &Bs[(srow + 64) * 32 + scol]);
    __syncthreads();
    short8 a[4], b[4];
#pragma unroll
    for (int m = 0; m < 4; ++m)
      a[m] = *(const short8*)&As[(wr * 64 + m * 16 + lr) * 32 + g * 8];
#pragma unroll
    for (int n = 0; n < 4; ++n)
      b[n] = *(const short8*)&Bs[(wc * 64 + n * 16 + lr) * 32 + g * 8];
#pragma unroll
    for (int m = 0; m < 4; ++m)
#pragma unroll
      for (int n = 0; n < 4; ++n)
        acc[m][n] = __builtin_amdgcn_mfma_f32_16x16x32_bf16(a[m], b[n], acc[m][n], 0, 0, 0);
    __syncthreads();
  }
  const float QSCALE = 0.125f * 1.4426950408889634f;
#pragma unroll
  for (int m = 0; m < 4; ++m) {
#pragma unroll
    for (int n = 0; n < 4; ++n) {
      int col = tn * 128 + wc * 64 + n * 16 + lr;
      float bv = bias[col];
      int sec = (col >= 1536) ? 2 : ((col >= 768) ? 1 : 0);
      int c = col - sec * 768;
      int hh = c >> 6, d = c & 63;
#pragma unroll
      for (int j = 0; j < 4; ++j) {
        int row = tm * 128 + wr * 64 + m * 16 + g * 4 + j;
        int bb = row >> 11, nn = row & 2047;
        size_t dst = (((size_t)(bb * 12 + hh) << 11) + nn) * 64 + d;
        float outv = acc[m][n][j] + bv;
        if (sec == 0) {
          Qo[dst] = f32_to_bf16(outv * QSCALE);
        } else if (sec == 1) {
          Ko[dst] = f32_to_bf16(outv);
        } else {
          Vo[dst] = f32_to_bf16(outv);
        }
      }
    }
  }
}

// ---------------- GEMM2: 64x64 tile, grid (64,12)=768 blocks ----------------
__global__ __launch_bounds__(256) void k_gemm2(const unsigned short* __restrict__ A,
                                               const unsigned short* __restrict__ Bt,
                                               const float* __restrict__ bias,
                                               float* __restrict__ C,
                                               int M, int N, int K) {
  __shared__ __align__(16) unsigned short As[64 * 32];
  __shared__ __align__(16) unsigned short Bs[64 * 32];
  int tid = threadIdx.x;
  int tm = blockIdx.x, tn = blockIdx.y;
  int lane = tid & 63, wid = tid >> 6;
  int wr = wid >> 1, wc = wid & 1;
  int g = lane >> 4, lr = lane & 15;
  f32x4 acc[2][2] = {};
  int srow = tid >> 2;
  int scol = (tid & 3) * 8;
  const unsigned short* Ab = A + (size_t)tm * 64 * K;
  const unsigned short* Bb = Bt + (size_t)tn * 64 * K;
  for (int k0 = 0; k0 < K; k0 += 32) {
    gld_lds16(Ab + (size_t)srow * K + k0 + scol, &As[srow * 32 + scol]);
    gld_lds16(Bb + (size_t)srow * K + k0 + scol, &Bs[srow * 32 + scol]);
    __syncthreads();
    short8 a[2], b[2];
#pragma unroll
    for (int m = 0; m < 2; ++m)
      a[m] = *(const short8*)&As[(wr * 32 + m * 16 + lr) * 32 + g * 8];
#pragma unroll
    for (int n = 0; n < 2; ++n)
      b[n] = *(const short8*)&Bs[(wc * 32 + n * 16 + lr) * 32 + g * 8];
#pragma unroll
    for (int m = 0; m < 2; ++m)
#pragma unroll
      for (int n = 0; n < 2; ++n)
        acc[m][n] = __builtin_amdgcn_mfma_f32_16x16x32_bf16(a[m], b[n], acc[m][n], 0, 0, 0);
    __syncthreads();
  }
#pragma unroll
  for (int m = 0; m < 2; ++m) {
#pragma unroll
    for (int n = 0; n < 2; ++n) {
      int col = tn * 64 + wc * 32 + n * 16 + lr;
      float bv = bias[col];
#pragma unroll
      for (int j = 0; j < 4; ++j) {
        int row = tm * 64 + wr * 32 + m * 16 + g * 4 + j;
        C[(size_t)row * N + col] = acc[m][n][j] + bv;
      }
    }
  }
}

// V transpose: Vc [24][2048][64] -> Vt [24][64][2048]
__global__ __launch_bounds__(256) void k_v_transpose(const unsigned short* __restrict__ Vc,
                                                     unsigned short* __restrict__ Vt) {
  int bh = blockIdx.x;  // 24
  int nt = blockIdx.y;  // 32
  __shared__ unsigned short s[64][65];
  int tid = threadIdx.x;
  int r = tid >> 2;
#pragma unroll
  for (int p = 0; p < 2; ++p) {
    int c = (tid & 3) + p * 4;
    short8 v = *(const short8*)&Vc[((size_t)(bh * 2048 + nt * 64 + r)) * 64 + c * 8];
#pragma unroll
    for (int ii = 0; ii < 8; ++ii) s[r][c * 8 + ii] = (unsigned short)v[ii];
  }
  __syncthreads();
  int d = tid >> 2;
#pragma unroll
  for (int p = 0; p < 2; ++p) {
    int c = (tid & 3) + p * 4;
    short8 w;
#pragma unroll
    for (int ii = 0; ii < 8; ++ii) w[ii] = (short)s[c * 8 + ii][d];
    *(short8*)&Vt[((size_t)bh * 64 + d) * 2048 + nt * 64 + c * 8] = w;
  }
}

// ------------- flash attention: 32x32 MFMA, in-register P, split-k ----------
// 4 waves x (32 q, 32 k-half) = 64 q/block, KV tile 64, dbuf. Grid (24,32)=768
// -> 3 blocks x 4 waves = 12 waves/CU. Wave (qh,kh): qh = q-half, kh = k-half
// of each KV tile. Fixed-offset softmax => partial O,l merge linearly at the
// epilogue via one LDS roundtrip (kh=1 writes, kh=0 adds). LDS 32KB.

#define ATTN_STAGE(KSB, VSB, T)                                                          \
  {                                                                                      \
    int kv0 = (T) * 64;                                                                  \
    _Pragma("unroll") for (int it = 0; it < 2; ++it) {                                   \
      int L = tid + it * 256;                                                            \
      int rw = L >> 3, s7 = L & 7;                                                       \
      gld_lds16(Kb + (size_t)(khead + kv0 + rw) * 64 + ((s7 ^ (rw & 7)) * 8),            \
                &KSB[L * 8]);                                                            \
      gld_lds16(Vt + (size_t)(vhead + rw) * 2048 + kv0 + ((s7 ^ (rw & 7)) * 8),          \
                &VSB[L * 8]);                                                            \
    }                                                                                    \
  }

// Build two PV A-frags (local ks 0,1) from this wave's 32x32 P accumulator S.
// w_low = cvtpk(S[b],S[b+1]) (vdst), w_high = cvtpk(S[b+4],S[b+5]) (vsrc):
// permlane32_swap exchanges w_low.hi <-> w_high.lo.
#define BUILD_PA(S)                                                                      \
  {                                                                                      \
    unsigned int b0, a0, e0, c0;                                                         \
    asm("v_cvt_pk_bf16_f32 %0, %1, %2" : "=v"(b0) : "v"(S[0]), "v"(S[1]));               \
    asm("v_cvt_pk_bf16_f32 %0, %1, %2" : "=v"(a0) : "v"(S[4]), "v"(S[5]));               \
    asm("v_permlane32_swap_b32 %0, %1" : "+v"(b0), "+v"(a0));                            \
    asm("v_cvt_pk_bf16_f32 %0, %1, %2" : "=v"(e0) : "v"(S[2]), "v"(S[3]));               \
    asm("v_cvt_pk_bf16_f32 %0, %1, %2" : "=v"(c0) : "v"(S[6]), "v"(S[7]));               \
    asm("v_permlane32_swap_b32 %0, %1" : "+v"(e0), "+v"(c0));                            \
    paw[0][0] = b0; paw[0][1] = e0; paw[0][2] = a0; paw[0][3] = c0;                      \
    unsigned int b1, a1, e1, c1;                                                         \
    asm("v_cvt_pk_bf16_f32 %0, %1, %2" : "=v"(b1) : "v"(S[8]), "v"(S[9]));               \
    asm("v_cvt_pk_bf16_f32 %0, %1, %2" : "=v"(a1) : "v"(S[12]), "v"(S[13]));             \
    asm("v_permlane32_swap_b32 %0, %1" : "+v"(b1), "+v"(a1));                            \
    asm("v_cvt_pk_bf16_f32 %0, %1, %2" : "=v"(e1) : "v"(S[10]), "v"(S[11]));             \
    asm("v_cvt_pk_bf16_f32 %0, %1, %2" : "=v"(c1) : "v"(S[14]), "v"(S[15]));             \
    asm("v_permlane32_swap_b32 %0, %1" : "+v"(e1), "+v"(c1));                            \
    paw[1][0] = b1; paw[1][1] = e1; paw[1][2] = a1; paw[1][3] = c1;                      \
  }

#define PROC_TILE(KSB, VSB)                                                              \
  {                                                                                      \
    f32x16 sa = {};                                                                      \
    __builtin_amdgcn_s_setprio(1);                                                       \
    _Pragma("unroll") for (int ds = 0; ds < 4; ++ds) {                                   \
      short8 kf = *(const short8*)&KSB[(kh * 32 + ln31) * 64 + (((ds * 2 + hi) ^ ln7) * 8)]; \
      sa = __builtin_amdgcn_mfma_f32_32x32x16_bf16(kf, qf[ds], sa, 0, 0, 0);             \
    }                                                                                    \
    __builtin_amdgcn_s_setprio(0);                                                       \
    _Pragma("unroll") for (int i = 0; i < 16; ++i) {                                     \
      float pv = exp2f(sa[i]);                                                           \
      sa[i] = pv;                                                                        \
      lrun += pv;                                                                        \
    }                                                                                    \
    unsigned int paw[2][4];                                                              \
    BUILD_PA(sa)                                                                         \
    __builtin_amdgcn_s_setprio(1);                                                       \
    _Pragma("unroll") for (int kl = 0; kl < 2; ++kl) {                                   \
      union {                                                                            \
        unsigned int u[4];                                                               \
        short8 s8;                                                                       \
      } pu;                                                                              \
      pu.u[0] = paw[kl][0];                                                              \
      pu.u[1] = paw[kl][1];                                                              \
      pu.u[2] = paw[kl][2];                                                              \
      pu.u[3] = paw[kl][3];                                                              \
      int ksg = kh * 2 + kl;                                                             \
      short8 vb0 = *(const short8*)&VSB[ln31 * 64 + (((ksg * 2 + hi) ^ ln7) * 8)];       \
      short8 vb1 = *(const short8*)&VSB[(32 + ln31) * 64 + (((ksg * 2 + hi) ^ ln7) * 8)]; \
      oacc0 = __builtin_amdgcn_mfma_f32_32x32x16_bf16(pu.s8, vb0, oacc0, 0, 0, 0);       \
      oacc1 = __builtin_amdgcn_mfma_f32_32x32x16_bf16(pu.s8, vb1, oacc1, 0, 0, 0);       \
    }                                                                                    \
    __builtin_amdgcn_s_setprio(0);                                                       \
  }

__global__ __launch_bounds__(256, 4) void k_attn(const unsigned short* __restrict__ Qb,
                                                 const unsigned short* __restrict__ Kb,
                                                 const unsigned short* __restrict__ Vt,
                                                 unsigned short* __restrict__ Xh) {
  int bh = blockIdx.x;  // 24
  int qb = blockIdx.y;  // 32
  int b = bh / 12, h = bh - b * 12;
  __shared__ __align__(16) unsigned short LDSbuf[4 * 64 * 64];
  unsigned short* Ks0 = LDSbuf;
  unsigned short* Vs0 = LDSbuf + 64 * 64;
  unsigned short* Ks1 = LDSbuf + 2 * 64 * 64;
  unsigned short* Vs1 = LDSbuf + 3 * 64 * 64;
  int tid = threadIdx.x;
  int wid = tid >> 6, lane = tid & 63;
  int qh = wid >> 1, kh = wid & 1;
  int ln31 = lane & 31, hi = lane >> 5, ln7 = lane & 7;
  int khead = bh * 2048;
  int vhead = bh * 64;
  int q0 = qb * 64 + qh * 32;

  // Q B-operand frags: lane holds Q[q0+ln31][ds*16 + hi*8 + e]
  short8 qf[4];
#pragma unroll
  for (int ds = 0; ds < 4; ++ds)
    qf[ds] = *(const short8*)&Qb[(size_t)(khead + q0 + ln31) * 64 + ds * 16 + hi * 8];

  float lrun = 0.f;
  f32x16 oacc0 = {}, oacc1 = {};

  ATTN_STAGE(Ks0, Vs0, 0);
  __syncthreads();
#pragma unroll 1
  for (int tt = 0; tt < 16; ++tt) {
    ATTN_STAGE(Ks1, Vs1, 2 * tt + 1);
    PROC_TILE(Ks0, Vs0);
    __syncthreads();
    if (tt < 15) ATTN_STAGE(Ks0, Vs0, 2 * tt + 2);
    PROC_TILE(Ks1, Vs1);
    __syncthreads();
  }

  // combine hi-halves (k sub-groups within this wave's k-half; same q)
  lrun += __shfl_xor(lrun, 32, 64);

  // merge k-halves across wave pairs via LDS scratch (reuse staging buffers)
  float* scr = (float*)LDSbuf;  // [2 qh][64 lane][33]
  if (kh == 1) {
    float* p = scr + (size_t)(qh * 64 + lane) * 33;
#pragma unroll
    for (int i = 0; i < 16; ++i) {
      p[i] = oacc0[i];
      p[16 + i] = oacc1[i];
    }
    p[32] = lrun;
  }
  __syncthreads();
  if (kh == 0) {
    float* p = scr + (size_t)(qh * 64 + lane) * 33;
#pragma unroll
    for (int i = 0; i < 16; ++i) {
      oacc0[i] += p[i];
      oacc1[i] += p[16 + i];
    }
    lrun += p[32];
    float linv = 1.0f / lrun;
#pragma unroll
    for (int r = 0; r < 16; ++r) {
      int qrow = (r & 3) + 8 * (r >> 2) + 4 * hi;
      float lf = __shfl(linv, qrow, 64);
      int grow = b * 2048 + q0 + qrow;
      int colb = h * 64 + ln31;
      Xh[(size_t)grow * 768 + colb] = f32_to_bf16(oacc0[r] * lf);
      Xh[(size_t)grow * 768 + colb + 32] = f32_to_bf16(oacc1[r] * lf);
    }
  }
}

// ---------------- launch ----------------
extern "C" void kernel_launch(void* const* d_in, const int* in_sizes, int n_in,
                              void* d_out, int out_size, void* d_ws, size_t ws_size,
                              hipStream_t stream) {
  const float* x = (const float*)d_in[0];      // [2,2048,768]
  const float* W_qkv = (const float*)d_in[1];  // [768,2304]
  const float* b_qkv = (const float*)d_in[2];  // [2304]
  const float* W_out = (const float*)d_in[3];  // [768,768]
  const float* b_out = (const float*)d_in[4];  // [768]
  float* out = (float*)d_out;                  // [4096,768]
  char* ws = (char*)d_ws;

  unsigned short* Xh = (unsigned short*)(ws + 0);           // 4096x768 bf16 (attn out H)
  unsigned short* Xb = (unsigned short*)(ws + 18874368);    // 4096x768 bf16 (x cast)
  unsigned short* Wq_t = (unsigned short*)(ws + 25165824);  // 2304x768 bf16
  unsigned short* Wo_t = (unsigned short*)(ws + 28704768);  // 768x768 bf16
  unsigned short* Qb = (unsigned short*)(ws + 32243712);    // 24x2048x64 (pre-scaled)
  unsigned short* Kb = (unsigned short*)(ws + 38535168);    // 24x2048x64
  unsigned short* Vc = (unsigned short*)(ws + 44826624);    // 24x2048x64
  unsigned short* Vt = (unsigned short*)(ws + 51118080);    // 24x64x2048

  k_cast_bf16<<<(4096 * 768 / 8 + 255) / 256, 256, 0, stream>>>(x, Xb, 4096 * 768 / 8);
  k_cast_Bt<<<dim3(24, 72), 256, 0, stream>>>(W_qkv, Wq_t, 768, 2304);
  k_cast_Bt<<<dim3(24, 24), 256, 0, stream>>>(W_out, Wo_t, 768, 768);
  k_gemm_qkv<<<dim3(32, 18), 256, 0, stream>>>(Xb, Wq_t, b_qkv, 4096, 2304, 768, Qb, Kb, Vc);
  k_v_transpose<<<dim3(24, 32), 256, 0, stream>>>(Vc, Vt);
  k_attn<<<dim3(24, 32), 256, 0, stream>>>(Qb, Kb, Vt, Xh);
  k_gemm2<<<dim3(64, 12), 256, 0, stream>>>(Xh, Wo_t, b_out, out, 4096, 768, 768);
}

// Round 16
// 100.944 us; speedup vs baseline: 1.1709x; 1.0496x over previous
//
#include <hip/hip_runtime.h>

#define DEVI __device__ __forceinline__

typedef __attribute__((ext_vector_type(8))) short short8;
typedef __attribute__((ext_vector_type(4))) float f32x4;
typedef __attribute__((ext_vector_type(16))) float f32x16;

DEVI unsigned short f32_to_bf16(float f) {
  unsigned int u = __float_as_uint(f);
  u += 0x7fffu + ((u >> 16) & 1u);
  return (unsigned short)(u >> 16);
}
DEVI float bf16_to_f32(unsigned short h) {
  return __uint_as_float(((unsigned int)h) << 16);
}

DEVI void gld_lds16(const void* g, void* l) {
  __builtin_amdgcn_global_load_lds(
      (__attribute__((address_space(1))) void*)(g),
      (__attribute__((address_space(3))) void*)(l), 16, 0, 0);
}

// ------------- merged prep: x cast + W_qkv transpose + W_out transpose ------
// grid.x: [0,1536) cast x (1536*256*8 = 4096*768 elems); [1536,3264) Wq_t
// (24 ktiles x 72 ntiles); [3264,3840) Wo_t (24x24)
__global__ __launch_bounds__(256) void k_prep(const float* __restrict__ x,
                                              const float* __restrict__ Wq,
                                              const float* __restrict__ Wo,
                                              unsigned short* __restrict__ Xb,
                                              unsigned short* __restrict__ Wq_t,
                                              unsigned short* __restrict__ Wo_t) {
  int blk = blockIdx.x;
  int tid = threadIdx.x;
  if (blk < 1536) {
    int i = blk * 256 + tid;
    const float* src = x + (size_t)i * 8;
    short8 v;
#pragma unroll
    for (int j = 0; j < 8; ++j) v[j] = (short)f32_to_bf16(src[j]);
    *(short8*)&Xb[(size_t)i * 8] = v;
    return;
  }
  const float* W;
  unsigned short* Wt;
  int kt, nt, K, N;
  if (blk < 3264) {
    int idx = blk - 1536;
    kt = idx % 24;
    nt = idx / 24;
    W = Wq;
    Wt = Wq_t;
    K = 768;
    N = 2304;
  } else {
    int idx = blk - 3264;
    kt = idx % 24;
    nt = idx / 24;
    W = Wo;
    Wt = Wo_t;
    K = 768;
    N = 768;
  }
  __shared__ float t[32][33];
#pragma unroll
  for (int p = 0; p < 4; ++p) {
    int idx = tid + p * 256;
    int rr = idx >> 5, cc = idx & 31;
    t[rr][cc] = W[(size_t)(kt * 32 + rr) * N + nt * 32 + cc];
  }
  __syncthreads();
#pragma unroll
  for (int p = 0; p < 4; ++p) {
    int idx = tid + p * 256;
    int rn = idx >> 5, ck = idx & 31;
    Wt[(size_t)(nt * 32 + rn) * K + kt * 32 + ck] = f32_to_bf16(t[ck][rn]);
  }
}

// ---------------- GEMM1: 128x128 tile, QKV scatter epilogue ----------------
// Q section is pre-scaled by 0.125*log2(e) so attn's exp2 takes raw MFMA output.
__global__ __launch_bounds__(256) void k_gemm_qkv(const unsigned short* __restrict__ A,
                                                  const unsigned short* __restrict__ Bt,
                                                  const float* __restrict__ bias,
                                                  int M, int N, int K,
                                                  unsigned short* __restrict__ Qo,
                                                  unsigned short* __restrict__ Ko,
                                                  unsigned short* __restrict__ Vo) {
  __shared__ __align__(16) unsigned short As[128 * 32];
  __shared__ __align__(16) unsigned short Bs[128 * 32];
  int tid = threadIdx.x;
  int tm = blockIdx.x, tn = blockIdx.y;
  int lane = tid & 63, wid = tid >> 6;
  int wr = wid >> 1, wc = wid & 1;
  int g = lane >> 4, lr = lane & 15;
  f32x4 acc[4][4] = {};
  int srow = tid >> 2;
  int scol = (tid & 3) * 8;
  const unsigned short* Ab = A + (size_t)tm * 128 * K;
  const unsigned short* Bb = Bt + (size_t)tn * 128 * K;
  for (int k0 = 0; k0 < K; k0 += 32) {
    gld_lds16(Ab + (size_t)srow * K + k0 + scol, &As[srow * 32 + scol]);
    gld_lds16(Ab + (size_t)(srow + 64) * K + k0 + scol, &As[(srow + 64) * 32 + scol]);
    gld_lds16(Bb + (size_t)srow * K + k0 + scol, &Bs[srow * 32 + scol]);
    gld_lds16(Bb + (size_t)(srow + 64) * K + k0 + scol, &Bs[(srow + 64) * 32 + scol]);
    __syncthreads();
    short8 a[4], b[4];
#pragma unroll
    for (int m = 0; m < 4; ++m)
      a[m] = *(const short8*)&As[(wr * 64 + m * 16 + lr) * 32 + g * 8];
#pragma unroll
    for (int n = 0; n < 4; ++n)
      b[n] = *(const short8*)&Bs[(wc * 64 + n * 16 + lr) * 32 + g * 8];
#pragma unroll
    for (int m = 0; m < 4; ++m)
#pragma unroll
      for (int n = 0; n < 4; ++n)
        acc[m][n] = __builtin_amdgcn_mfma_f32_16x16x32_bf16(a[m], b[n], acc[m][n], 0, 0, 0);
    __syncthreads();
  }
  const float QSCALE = 0.125f * 1.4426950408889634f;
#pragma unroll
  for (int m = 0; m < 4; ++m) {
#pragma unroll
    for (int n = 0; n < 4; ++n) {
      int col = tn * 128 + wc * 64 + n * 16 + lr;
      float bv = bias[col];
      int sec = (col >= 1536) ? 2 : ((col >= 768) ? 1 : 0);
      int c = col - sec * 768;
      int hh = c >> 6, d = c & 63;
#pragma unroll
      for (int j = 0; j < 4; ++j) {
        int row = tm * 128 + wr * 64 + m * 16 + g * 4 + j;
        int bb = row >> 11, nn = row & 2047;
        size_t dst = (((size_t)(bb * 12 + hh) << 11) + nn) * 64 + d;
        float outv = acc[m][n][j] + bv;
        if (sec == 0) {
          Qo[dst] = f32_to_bf16(outv * QSCALE);
        } else if (sec == 1) {
          Ko[dst] = f32_to_bf16(outv);
        } else {
          Vo[dst] = f32_to_bf16(outv);
        }
      }
    }
  }
}

// ---------------- GEMM2: 64x64 tile, grid (64,12)=768 blocks ----------------
__global__ __launch_bounds__(256) void k_gemm2(const unsigned short* __restrict__ A,
                                               const unsigned short* __restrict__ Bt,
                                               const float* __restrict__ bias,
                                               float* __restrict__ C,
                                               int M, int N, int K) {
  __shared__ __align__(16) unsigned short As[64 * 32];
  __shared__ __align__(16) unsigned short Bs[64 * 32];
  int tid = threadIdx.x;
  int tm = blockIdx.x, tn = blockIdx.y;
  int lane = tid & 63, wid = tid >> 6;
  int wr = wid >> 1, wc = wid & 1;
  int g = lane >> 4, lr = lane & 15;
  f32x4 acc[2][2] = {};
  int srow = tid >> 2;
  int scol = (tid & 3) * 8;
  const unsigned short* Ab = A + (size_t)tm * 64 * K;
  const unsigned short* Bb = Bt + (size_t)tn * 64 * K;
  for (int k0 = 0; k0 < K; k0 += 32) {
    gld_lds16(Ab + (size_t)srow * K + k0 + scol, &As[srow * 32 + scol]);
    gld_lds16(Bb + (size_t)srow * K + k0 + scol, &Bs[srow * 32 + scol]);
    __syncthreads();
    short8 a[2], b[2];
#pragma unroll
    for (int m = 0; m < 2; ++m)
      a[m] = *(const short8*)&As[(wr * 32 + m * 16 + lr) * 32 + g * 8];
#pragma unroll
    for (int n = 0; n < 2; ++n)
      b[n] = *(const short8*)&Bs[(wc * 32 + n * 16 + lr) * 32 + g * 8];
#pragma unroll
    for (int m = 0; m < 2; ++m)
#pragma unroll
      for (int n = 0; n < 2; ++n)
        acc[m][n] = __builtin_amdgcn_mfma_f32_16x16x32_bf16(a[m], b[n], acc[m][n], 0, 0, 0);
    __syncthreads();
  }
#pragma unroll
  for (int m = 0; m < 2; ++m) {
#pragma unroll
    for (int n = 0; n < 2; ++n) {
      int col = tn * 64 + wc * 32 + n * 16 + lr;
      float bv = bias[col];
#pragma unroll
      for (int j = 0; j < 4; ++j) {
        int row = tm * 64 + wr * 32 + m * 16 + g * 4 + j;
        C[(size_t)row * N + col] = acc[m][n][j] + bv;
      }
    }
  }
}

// V transpose: Vc [24][2048][64] -> Vt [24][64][2048]
__global__ __launch_bounds__(256) void k_v_transpose(const unsigned short* __restrict__ Vc,
                                                     unsigned short* __restrict__ Vt) {
  int bh = blockIdx.x;  // 24
  int nt = blockIdx.y;  // 32
  __shared__ unsigned short s[64][65];
  int tid = threadIdx.x;
  int r = tid >> 2;
#pragma unroll
  for (int p = 0; p < 2; ++p) {
    int c = (tid & 3) + p * 4;
    short8 v = *(const short8*)&Vc[((size_t)(bh * 2048 + nt * 64 + r)) * 64 + c * 8];
#pragma unroll
    for (int ii = 0; ii < 8; ++ii) s[r][c * 8 + ii] = (unsigned short)v[ii];
  }
  __syncthreads();
  int d = tid >> 2;
#pragma unroll
  for (int p = 0; p < 2; ++p) {
    int c = (tid & 3) + p * 4;
    short8 w;
#pragma unroll
    for (int ii = 0; ii < 8; ++ii) w[ii] = (short)s[c * 8 + ii][d];
    *(short8*)&Vt[((size_t)bh * 64 + d) * 2048 + nt * 64 + c * 8] = w;
  }
}

// ------------- flash attention: 32x32 MFMA, in-register P, split-k ----------
// 4 waves x (32 q, 32 k-half) = 64 q/block, KV tile 64, dbuf. Grid (24,32)=768
// -> 3 blocks x 4 waves = 12 waves/CU. Fixed-offset softmax => partial O,l
// merge linearly at the epilogue via one LDS roundtrip. LDS 32KB.
// exp via exp2f (lowers to v_exp_f32 WITH compiler-managed TRANS hazard
// handling -- raw inline-asm v_exp_f32 lacks the required wait state, R15).

#define ATTN_STAGE(KSB, VSB, T)                                                          \
  {                                                                                      \
    int kv0 = (T) * 64;                                                                  \
    _Pragma("unroll") for (int it = 0; it < 2; ++it) {                                   \
      int L = tid + it * 256;                                                            \
      int rw = L >> 3, s7 = L & 7;                                                       \
      gld_lds16(Kb + (size_t)(khead + kv0 + rw) * 64 + ((s7 ^ (rw & 7)) * 8),            \
                &KSB[L * 8]);                                                            \
      gld_lds16(Vt + (size_t)(vhead + rw) * 2048 + kv0 + ((s7 ^ (rw & 7)) * 8),          \
                &VSB[L * 8]);                                                            \
    }                                                                                    \
  }

// Build two PV A-frags (local ks 0,1) from this wave's 32x32 P accumulator S.
// w_low = cvtpk(S[b],S[b+1]) (vdst), w_high = cvtpk(S[b+4],S[b+5]) (vsrc):
// permlane32_swap exchanges w_low.hi <-> w_high.lo.
#define BUILD_PA(S)                                                                      \
  {                                                                                      \
    unsigned int b0, a0, e0, c0;                                                         \
    asm("v_cvt_pk_bf16_f32 %0, %1, %2" : "=v"(b0) : "v"(S[0]), "v"(S[1]));               \
    asm("v_cvt_pk_bf16_f32 %0, %1, %2" : "=v"(a0) : "v"(S[4]), "v"(S[5]));               \
    asm("v_permlane32_swap_b32 %0, %1" : "+v"(b0), "+v"(a0));                            \
    asm("v_cvt_pk_bf16_f32 %0, %1, %2" : "=v"(e0) : "v"(S[2]), "v"(S[3]));               \
    asm("v_cvt_pk_bf16_f32 %0, %1, %2" : "=v"(c0) : "v"(S[6]), "v"(S[7]));               \
    asm("v_permlane32_swap_b32 %0, %1" : "+v"(e0), "+v"(c0));                            \
    paw[0][0] = b0; paw[0][1] = e0; paw[0][2] = a0; paw[0][3] = c0;                      \
    unsigned int b1, a1, e1, c1;                                                         \
    asm("v_cvt_pk_bf16_f32 %0, %1, %2" : "=v"(b1) : "v"(S[8]), "v"(S[9]));               \
    asm("v_cvt_pk_bf16_f32 %0, %1, %2" : "=v"(a1) : "v"(S[12]), "v"(S[13]));             \
    asm("v_permlane32_swap_b32 %0, %1" : "+v"(b1), "+v"(a1));                            \
    asm("v_cvt_pk_bf16_f32 %0, %1, %2" : "=v"(e1) : "v"(S[10]), "v"(S[11]));             \
    asm("v_cvt_pk_bf16_f32 %0, %1, %2" : "=v"(c1) : "v"(S[14]), "v"(S[15]));             \
    asm("v_permlane32_swap_b32 %0, %1" : "+v"(e1), "+v"(c1));                            \
    paw[1][0] = b1; paw[1][1] = e1; paw[1][2] = a1; paw[1][3] = c1;                      \
  }

#define PROC_TILE(KSB, VSB)                                                              \
  {                                                                                      \
    f32x16 sa = {};                                                                      \
    __builtin_amdgcn_s_setprio(1);                                                       \
    _Pragma("unroll") for (int ds = 0; ds < 4; ++ds) {                                   \
      short8 kf = *(const short8*)&KSB[(kh * 32 + ln31) * 64 + (((ds * 2 + hi) ^ ln7) * 8)]; \
      sa = __builtin_amdgcn_mfma_f32_32x32x16_bf16(kf, qf[ds], sa, 0, 0, 0);             \
    }                                                                                    \
    __builtin_amdgcn_s_setprio(0);                                                       \
    _Pragma("unroll") for (int i = 0; i < 16; ++i) {                                     \
      float pv = exp2f(sa[i]);                                                           \
      sa[i] = pv;                                                                        \
      lrun += pv;                                                                        \
    }                                                                                    \
    unsigned int paw[2][4];                                                              \
    BUILD_PA(sa)                                                                         \
    __builtin_amdgcn_s_setprio(1);                                                       \
    _Pragma("unroll") for (int kl = 0; kl < 2; ++kl) {                                   \
      union {                                                                            \
        unsigned int u[4];                                                               \
        short8 s8;                                                                       \
      } pu;                                                                              \
      pu.u[0] = paw[kl][0];                                                              \
      pu.u[1] = paw[kl][1];                                                              \
      pu.u[2] = paw[kl][2];                                                              \
      pu.u[3] = paw[kl][3];                                                              \
      int ksg = kh * 2 + kl;                                                             \
      short8 vb0 = *(const short8*)&VSB[ln31 * 64 + (((ksg * 2 + hi) ^ ln7) * 8)];       \
      short8 vb1 = *(const short8*)&VSB[(32 + ln31) * 64 + (((ksg * 2 + hi) ^ ln7) * 8)]; \
      oacc0 = __builtin_amdgcn_mfma_f32_32x32x16_bf16(pu.s8, vb0, oacc0, 0, 0, 0);       \
      oacc1 = __builtin_amdgcn_mfma_f32_32x32x16_bf16(pu.s8, vb1, oacc1, 0, 0, 0);       \
    }                                                                                    \
    __builtin_amdgcn_s_setprio(0);                                                       \
  }

__global__ __launch_bounds__(256, 4) void k_attn(const unsigned short* __restrict__ Qb,
                                                 const unsigned short* __restrict__ Kb,
                                                 const unsigned short* __restrict__ Vt,
                                                 unsigned short* __restrict__ Xh) {
  int bh = blockIdx.x;  // 24
  int qb = blockIdx.y;  // 32
  int b = bh / 12, h = bh - b * 12;
  __shared__ __align__(16) unsigned short LDSbuf[4 * 64 * 64];
  unsigned short* Ks0 = LDSbuf;
  unsigned short* Vs0 = LDSbuf + 64 * 64;
  unsigned short* Ks1 = LDSbuf + 2 * 64 * 64;
  unsigned short* Vs1 = LDSbuf + 3 * 64 * 64;
  int tid = threadIdx.x;
  int wid = tid >> 6, lane = tid & 63;
  int qh = wid >> 1, kh = wid & 1;
  int ln31 = lane & 31, hi = lane >> 5, ln7 = lane & 7;
  int khead = bh * 2048;
  int vhead = bh * 64;
  int q0 = qb * 64 + qh * 32;

  // Q B-operand frags: lane holds Q[q0+ln31][ds*16 + hi*8 + e]
  short8 qf[4];
#pragma unroll
  for (int ds = 0; ds < 4; ++ds)
    qf[ds] = *(const short8*)&Qb[(size_t)(khead + q0 + ln31) * 64 + ds * 16 + hi * 8];

  float lrun = 0.f;
  f32x16 oacc0 = {}, oacc1 = {};

  ATTN_STAGE(Ks0, Vs0, 0);
  __syncthreads();
#pragma unroll 1
  for (int tt = 0; tt < 16; ++tt) {
    ATTN_STAGE(Ks1, Vs1, 2 * tt + 1);
    PROC_TILE(Ks0, Vs0);
    __syncthreads();
    if (tt < 15) ATTN_STAGE(Ks0, Vs0, 2 * tt + 2);
    PROC_TILE(Ks1, Vs1);
    __syncthreads();
  }

  // combine hi-halves (k sub-groups within this wave's k-half; same q)
  lrun += __shfl_xor(lrun, 32, 64);

  // merge k-halves across wave pairs via LDS scratch (reuse staging buffers)
  float* scr = (float*)LDSbuf;  // [2 qh][64 lane][33]
  if (kh == 1) {
    float* p = scr + (size_t)(qh * 64 + lane) * 33;
#pragma unroll
    for (int i = 0; i < 16; ++i) {
      p[i] = oacc0[i];
      p[16 + i] = oacc1[i];
    }
    p[32] = lrun;
  }
  __syncthreads();
  if (kh == 0) {
    float* p = scr + (size_t)(qh * 64 + lane) * 33;
#pragma unroll
    for (int i = 0; i < 16; ++i) {
      oacc0[i] += p[i];
      oacc1[i] += p[16 + i];
    }
    lrun += p[32];
    float linv = 1.0f / lrun;
#pragma unroll
    for (int r = 0; r < 16; ++r) {
      int qrow = (r & 3) + 8 * (r >> 2) + 4 * hi;
      float lf = __shfl(linv, qrow, 64);
      int grow = b * 2048 + q0 + qrow;
      int colb = h * 64 + ln31;
      Xh[(size_t)grow * 768 + colb] = f32_to_bf16(oacc0[r] * lf);
      Xh[(size_t)grow * 768 + colb + 32] = f32_to_bf16(oacc1[r] * lf);
    }
  }
}

// ---------------- launch ----------------
extern "C" void kernel_launch(void* const* d_in, const int* in_sizes, int n_in,
                              void* d_out, int out_size, void* d_ws, size_t ws_size,
                              hipStream_t stream) {
  const float* x = (const float*)d_in[0];      // [2,2048,768]
  const float* W_qkv = (const float*)d_in[1];  // [768,2304]
  const float* b_qkv = (const float*)d_in[2];  // [2304]
  const float* W_out = (const float*)d_in[3];  // [768,768]
  const float* b_out = (const float*)d_in[4];  // [768]
  float* out = (float*)d_out;                  // [4096,768]
  char* ws = (char*)d_ws;

  unsigned short* Xh = (unsigned short*)(ws + 0);           // 4096x768 bf16 (attn out H)
  unsigned short* Xb = (unsigned short*)(ws + 18874368);    // 4096x768 bf16 (x cast)
  unsigned short* Wq_t = (unsigned short*)(ws + 25165824);  // 2304x768 bf16
  unsigned short* Wo_t = (unsigned short*)(ws + 28704768);  // 768x768 bf16
  unsigned short* Qb = (unsigned short*)(ws + 32243712);    // 24x2048x64 (pre-scaled)
  unsigned short* Kb = (unsigned short*)(ws + 38535168);    // 24x2048x64
  unsigned short* Vc = (unsigned short*)(ws + 44826624);    // 24x2048x64
  unsigned short* Vt = (unsigned short*)(ws + 51118080);    // 24x64x2048

  k_prep<<<3840, 256, 0, stream>>>(x, W_qkv, W_out, Xb, Wq_t, Wo_t);
  k_gemm_qkv<<<dim3(32, 18), 256, 0, stream>>>(Xb, Wq_t, b_qkv, 4096, 2304, 768, Qb, Kb, Vc);
  k_v_transpose<<<dim3(24, 32), 256, 0, stream>>>(Vc, Vt);
  k_attn<<<dim3(24, 32), 256, 0, stream>>>(Qb, Kb, Vt, Xh);
  k_gemm2<<<dim3(64, 12), 256, 0, stream>>>(Xh, Wo_t, b_out, out, 4096, 768, 768);
}

// Round 18
// 95.574 us; speedup vs baseline: 1.2367x; 1.0562x over previous
//
#include <hip/hip_runtime.h>

#define DEVI __device__ __forceinline__

typedef __attribute__((ext_vector_type(8))) short short8;
typedef __attribute__((ext_vector_type(4))) short s16x4;
typedef __attribute__((ext_vector_type(4))) float f32x4;
typedef __attribute__((ext_vector_type(16))) float f32x16;

DEVI unsigned short f32_to_bf16(float f) {
  unsigned int u = __float_as_uint(f);
  u += 0x7fffu + ((u >> 16) & 1u);
  return (unsigned short)(u >> 16);
}
DEVI float bf16_to_f32(unsigned short h) {
  return __uint_as_float(((unsigned int)h) << 16);
}

DEVI void gld_lds16(const void* g, void* l) {
  __builtin_amdgcn_global_load_lds(
      (__attribute__((address_space(1))) void*)(g),
      (__attribute__((address_space(3))) void*)(l), 16, 0, 0);
}

// ------------- merged prep: x cast + W_qkv transpose + W_out transpose ------
// grid.x: [0,1536) cast x (1536*256*8 = 4096*768 elems); [1536,3264) Wq_t
// (24 ktiles x 72 ntiles); [3264,3840) Wo_t (24x24)
__global__ __launch_bounds__(256) void k_prep(const float* __restrict__ x,
                                              const float* __restrict__ Wq,
                                              const float* __restrict__ Wo,
                                              unsigned short* __restrict__ Xb,
                                              unsigned short* __restrict__ Wq_t,
                                              unsigned short* __restrict__ Wo_t) {
  int blk = blockIdx.x;
  int tid = threadIdx.x;
  if (blk < 1536) {
    int i = blk * 256 + tid;
    const float* src = x + (size_t)i * 8;
    short8 v;
#pragma unroll
    for (int j = 0; j < 8; ++j) v[j] = (short)f32_to_bf16(src[j]);
    *(short8*)&Xb[(size_t)i * 8] = v;
    return;
  }
  const float* W;
  unsigned short* Wt;
  int kt, nt, K, N;
  if (blk < 3264) {
    int idx = blk - 1536;
    kt = idx % 24;
    nt = idx / 24;
    W = Wq;
    Wt = Wq_t;
    K = 768;
    N = 2304;
  } else {
    int idx = blk - 3264;
    kt = idx % 24;
    nt = idx / 24;
    W = Wo;
    Wt = Wo_t;
    K = 768;
    N = 768;
  }
  __shared__ float t[32][33];
#pragma unroll
  for (int p = 0; p < 4; ++p) {
    int idx = tid + p * 256;
    int rr = idx >> 5, cc = idx & 31;
    t[rr][cc] = W[(size_t)(kt * 32 + rr) * N + nt * 32 + cc];
  }
  __syncthreads();
#pragma unroll
  for (int p = 0; p < 4; ++p) {
    int idx = tid + p * 256;
    int rn = idx >> 5, ck = idx & 31;
    Wt[(size_t)(nt * 32 + rn) * K + kt * 32 + ck] = f32_to_bf16(t[ck][rn]);
  }
}

// ---------------- GEMM1: 128x64 tile, QKV scatter epilogue ------------------
// Grid (32,36) = 1152 blocks (~4.5/CU). Each 64-col tile lies wholly in one
// QKV section (768/64=12): sec = tn/12 is wave-uniform. V is written DIRECTLY
// transposed into Vt [24][64][2048] (4 consecutive n at fixed d -> s16x4).
// Q section pre-scaled by 0.125*log2(e) so attn's exp2 takes raw MFMA output.
__global__ __launch_bounds__(256) void k_gemm_qkv(const unsigned short* __restrict__ A,
                                                  const unsigned short* __restrict__ Bt,
                                                  const float* __restrict__ bias,
                                                  int M, int N, int K,
                                                  unsigned short* __restrict__ Qo,
                                                  unsigned short* __restrict__ Ko,
                                                  unsigned short* __restrict__ Vt) {
  __shared__ __align__(16) unsigned short As[128 * 32];
  __shared__ __align__(16) unsigned short Bs[64 * 32];
  int tid = threadIdx.x;
  int tm = blockIdx.x, tn = blockIdx.y;
  int lane = tid & 63, wid = tid >> 6;
  int g = lane >> 4, lr = lane & 15;
  f32x4 acc[2][4] = {};
  int srow = tid >> 2;
  int scol = (tid & 3) * 8;
  const unsigned short* Ab = A + (size_t)tm * 128 * K;
  const unsigned short* Bb = Bt + (size_t)tn * 64 * K;
  for (int k0 = 0; k0 < K; k0 += 32) {
    gld_lds16(Ab + (size_t)srow * K + k0 + scol, &As[srow * 32 + scol]);
    gld_lds16(Ab + (size_t)(srow + 64) * K + k0 + scol, &As[(srow + 64) * 32 + scol]);
    gld_lds16(Bb + (size_t)srow * K + k0 + scol, &Bs[srow * 32 + scol]);
    __syncthreads();
    short8 a[2], b[4];
#pragma unroll
    for (int m = 0; m < 2; ++m)
      a[m] = *(const short8*)&As[(wid * 32 + m * 16 + lr) * 32 + g * 8];
#pragma unroll
    for (int n = 0; n < 4; ++n)
      b[n] = *(const short8*)&Bs[(n * 16 + lr) * 32 + g * 8];
#pragma unroll
    for (int m = 0; m < 2; ++m)
#pragma unroll
      for (int n = 0; n < 4; ++n)
        acc[m][n] = __builtin_amdgcn_mfma_f32_16x16x32_bf16(a[m], b[n], acc[m][n], 0, 0, 0);
    __syncthreads();
  }
  const float QSCALE = 0.125f * 1.4426950408889634f;
  int sec = tn / 12;              // 0=Q, 1=K, 2=V (uniform per block)
  int cb = tn * 64 - sec * 768;   // section-local col base
#pragma unroll
  for (int m = 0; m < 2; ++m) {
#pragma unroll
    for (int n = 0; n < 4; ++n) {
      int c = cb + n * 16 + lr;
      int hh = c >> 6, d = c & 63;
      float bv = bias[tn * 64 + n * 16 + lr];
      int rowb = tm * 128 + wid * 32 + m * 16 + g * 4;
      int bb = rowb >> 11, nn = rowb & 2047;
      int bh = bb * 12 + hh;
      if (sec == 2) {
        s16x4 v4;
#pragma unroll
        for (int j = 0; j < 4; ++j) v4[j] = (short)f32_to_bf16(acc[m][n][j] + bv);
        *(s16x4*)&Vt[((size_t)bh * 64 + d) * 2048 + nn] = v4;
      } else {
        unsigned short* dst0 = (sec == 0) ? Qo : Ko;
        float sc = (sec == 0) ? QSCALE : 1.0f;
#pragma unroll
        for (int j = 0; j < 4; ++j) {
          size_t dst = (((size_t)bh << 11) + nn + j) * 64 + d;
          dst0[dst] = f32_to_bf16((acc[m][n][j] + bv) * sc);
        }
      }
    }
  }
}

// ---------------- GEMM2: 64x64 tile, grid (64,12)=768 blocks ----------------
__global__ __launch_bounds__(256) void k_gemm2(const unsigned short* __restrict__ A,
                                               const unsigned short* __restrict__ Bt,
                                               const float* __restrict__ bias,
                                               float* __restrict__ C,
                                               int M, int N, int K) {
  __shared__ __align__(16) unsigned short As[64 * 32];
  __shared__ __align__(16) unsigned short Bs[64 * 32];
  int tid = threadIdx.x;
  int tm = blockIdx.x, tn = blockIdx.y;
  int lane = tid & 63, wid = tid >> 6;
  int wr = wid >> 1, wc = wid & 1;
  int g = lane >> 4, lr = lane & 15;
  f32x4 acc[2][2] = {};
  int srow = tid >> 2;
  int scol = (tid & 3) * 8;
  const unsigned short* Ab = A + (size_t)tm * 64 * K;
  const unsigned short* Bb = Bt + (size_t)tn * 64 * K;
  for (int k0 = 0; k0 < K; k0 += 32) {
    gld_lds16(Ab + (size_t)srow * K + k0 + scol, &As[srow * 32 + scol]);
    gld_lds16(Bb + (size_t)srow * K + k0 + scol, &Bs[srow * 32 + scol]);
    __syncthreads();
    short8 a[2], b[2];
#pragma unroll
    for (int m = 0; m < 2; ++m)
      a[m] = *(const short8*)&As[(wr * 32 + m * 16 + lr) * 32 + g * 8];
#pragma unroll
    for (int n = 0; n < 2; ++n)
      b[n] = *(const short8*)&Bs[(wc * 32 + n * 16 + lr) * 32 + g * 8];
#pragma unroll
    for (int m = 0; m < 2; ++m)
#pragma unroll
      for (int n = 0; n < 2; ++n)
        acc[m][n] = __builtin_amdgcn_mfma_f32_16x16x32_bf16(a[m], b[n], acc[m][n], 0, 0, 0);
    __syncthreads();
  }
#pragma unroll
  for (int m = 0; m < 2; ++m) {
#pragma unroll
    for (int n = 0; n < 2; ++n) {
      int col = tn * 64 + wc * 32 + n * 16 + lr;
      float bv = bias[col];
#pragma unroll
      for (int j = 0; j < 4; ++j) {
        int row = tm * 64 + wr * 32 + m * 16 + g * 4 + j;
        C[(size_t)row * N + col] = acc[m][n][j] + bv;
      }
    }
  }
}

// ------------- flash attention: 32x32 MFMA, in-register P, split-k ----------
// 4 waves x (32 q, 32 k-half) = 64 q/block, KV tile 64, dbuf. Grid (24,32)=768
// -> 3 blocks x 4 waves = 12 waves/CU. Fixed-offset softmax => partial O,l
// merge linearly at the epilogue via one LDS roundtrip. LDS 32KB.
// exp via exp2f (lowers to v_exp_f32 WITH compiler-managed TRANS hazard
// handling -- raw inline-asm v_exp_f32 lacks the required wait state, R15).

#define ATTN_STAGE(KSB, VSB, T)                                                          \
  {                                                                                      \
    int kv0 = (T) * 64;                                                                  \
    _Pragma("unroll") for (int it = 0; it < 2; ++it) {                                   \
      int L = tid + it * 256;                                                            \
      int rw = L >> 3, s7 = L & 7;                                                       \
      gld_lds16(Kb + (size_t)(khead + kv0 + rw) * 64 + ((s7 ^ (rw & 7)) * 8),            \
                &KSB[L * 8]);                                                            \
      gld_lds16(Vt + (size_t)(vhead + rw) * 2048 + kv0 + ((s7 ^ (rw & 7)) * 8),          \
                &VSB[L * 8]);                                                            \
    }                                                                                    \
  }

// Build two PV A-frags (local ks 0,1) from this wave's 32x32 P accumulator S.
// w_low = cvtpk(S[b],S[b+1]) (vdst), w_high = cvtpk(S[b+4],S[b+5]) (vsrc):
// permlane32_swap exchanges w_low.hi <-> w_high.lo.
#define BUILD_PA(S)                                                                      \
  {                                                                                      \
    unsigned int b0, a0, e0, c0;                                                         \
    asm("v_cvt_pk_bf16_f32 %0, %1, %2" : "=v"(b0) : "v"(S[0]), "v"(S[1]));               \
    asm("v_cvt_pk_bf16_f32 %0, %1, %2" : "=v"(a0) : "v"(S[4]), "v"(S[5]));               \
    asm("v_permlane32_swap_b32 %0, %1" : "+v"(b0), "+v"(a0));                            \
    asm("v_cvt_pk_bf16_f32 %0, %1, %2" : "=v"(e0) : "v"(S[2]), "v"(S[3]));               \
    asm("v_cvt_pk_bf16_f32 %0, %1, %2" : "=v"(c0) : "v"(S[6]), "v"(S[7]));               \
    asm("v_permlane32_swap_b32 %0, %1" : "+v"(e0), "+v"(c0));                            \
    paw[0][0] = b0; paw[0][1] = e0; paw[0][2] = a0; paw[0][3] = c0;                      \
    unsigned int b1, a1, e1, c1;                                                         \
    asm("v_cvt_pk_bf16_f32 %0, %1, %2" : "=v"(b1) : "v"(S[8]), "v"(S[9]));               \
    asm("v_cvt_pk_bf16_f32 %0, %1, %2" : "=v"(a1) : "v"(S[12]), "v"(S[13]));             \
    asm("v_permlane32_swap_b32 %0, %1" : "+v"(b1), "+v"(a1));                            \
    asm("v_cvt_pk_bf16_f32 %0, %1, %2" : "=v"(e1) : "v"(S[10]), "v"(S[11]));             \
    asm("v_cvt_pk_bf16_f32 %0, %1, %2" : "=v"(c1) : "v"(S[14]), "v"(S[15]));             \
    asm("v_permlane32_swap_b32 %0, %1" : "+v"(e1), "+v"(c1));                            \
    paw[1][0] = b1; paw[1][1] = e1; paw[1][2] = a1; paw[1][3] = c1;                      \
  }

#define PROC_TILE(KSB, VSB)                                                              \
  {                                                                                      \
    f32x16 sa = {};                                                                      \
    __builtin_amdgcn_s_setprio(1);                                                       \
    _Pragma("unroll") for (int ds = 0; ds < 4; ++ds) {                                   \
      short8 kf = *(const short8*)&KSB[(kh * 32 + ln31) * 64 + (((ds * 2 + hi) ^ ln7) * 8)]; \
      sa = __builtin_amdgcn_mfma_f32_32x32x16_bf16(kf, qf[ds], sa, 0, 0, 0);             \
    }                                                                                    \
    __builtin_amdgcn_s_setprio(0);                                                       \
    _Pragma("unroll") for (int i = 0; i < 16; ++i) {                                     \
      float pv = exp2f(sa[i]);                                                           \
      sa[i] = pv;                                                                        \
      lrun += pv;                                                                        \
    }                                                                                    \
    unsigned int paw[2][4];                                                              \
    BUILD_PA(sa)                                                                         \
    __builtin_amdgcn_s_setprio(1);                                                       \
    _Pragma("unroll") for (int kl = 0; kl < 2; ++kl) {                                   \
      union {                                                                            \
        unsigned int u[4];                                                               \
        short8 s8;                                                                      \
      } pu;                                                                              \
      pu.u[0] = paw[kl][0];                                                              \
      pu.u[1] = paw[kl][1];                                                              \
      pu.u[2] = paw[kl][2];                                                              \
      pu.u[3] = paw[kl][3];                                                              \
      int ksg = kh * 2 + kl;                                                             \
      short8 vb0 = *(const short8*)&VSB[ln31 * 64 + (((ksg * 2 + hi) ^ ln7) * 8)];       \
      short8 vb1 = *(const short8*)&VSB[(32 + ln31) * 64 + (((ksg * 2 + hi) ^ ln7) * 8)]; \
      oacc0 = __builtin_amdgcn_mfma_f32_32x32x16_bf16(pu.s8, vb0, oacc0, 0, 0, 0);       \
      oacc1 = __builtin_amdgcn_mfma_f32_32x32x16_bf16(pu.s8, vb1, oacc1, 0, 0, 0);       \
    }                                                                                    \
    __builtin_amdgcn_s_setprio(0);                                                       \
  }

__global__ __launch_bounds__(256, 4) void k_attn(const unsigned short* __restrict__ Qb,
                                                 const unsigned short* __restrict__ Kb,
                                                 const unsigned short* __restrict__ Vt,
                                                 unsigned short* __restrict__ Xh) {
  int bh = blockIdx.x;  // 24
  int qb = blockIdx.y;  // 32
  int b = bh / 12, h = bh - b * 12;
  __shared__ __align__(16) unsigned short LDSbuf[4 * 64 * 64];
  unsigned short* Ks0 = LDSbuf;
  unsigned short* Vs0 = LDSbuf + 64 * 64;
  unsigned short* Ks1 = LDSbuf + 2 * 64 * 64;
  unsigned short* Vs1 = LDSbuf + 3 * 64 * 64;
  int tid = threadIdx.x;
  int wid = tid >> 6, lane = tid & 63;
  int qh = wid >> 1, kh = wid & 1;
  int ln31 = lane & 31, hi = lane >> 5, ln7 = lane & 7;
  int khead = bh * 2048;
  int vhead = bh * 64;
  int q0 = qb * 64 + qh * 32;

  // Q B-operand frags: lane holds Q[q0+ln31][ds*16 + hi*8 + e]
  short8 qf[4];
#pragma unroll
  for (int ds = 0; ds < 4; ++ds)
    qf[ds] = *(const short8*)&Qb[(size_t)(khead + q0 + ln31) * 64 + ds * 16 + hi * 8];

  float lrun = 0.f;
  f32x16 oacc0 = {}, oacc1 = {};

  ATTN_STAGE(Ks0, Vs0, 0);
  __syncthreads();
#pragma unroll 1
  for (int tt = 0; tt < 16; ++tt) {
    ATTN_STAGE(Ks1, Vs1, 2 * tt + 1);
    PROC_TILE(Ks0, Vs0);
    __syncthreads();
    if (tt < 15) ATTN_STAGE(Ks0, Vs0, 2 * tt + 2);
    PROC_TILE(Ks1, Vs1);
    __syncthreads();
  }

  // combine hi-halves (k sub-groups within this wave's k-half; same q)
  lrun += __shfl_xor(lrun, 32, 64);

  // merge k-halves across wave pairs via LDS scratch (reuse staging buffers)
  float* scr = (float*)LDSbuf;  // [2 qh][64 lane][33]
  if (kh == 1) {
    float* p = scr + (size_t)(qh * 64 + lane) * 33;
#pragma unroll
    for (int i = 0; i < 16; ++i) {
      p[i] = oacc0[i];
      p[16 + i] = oacc1[i];
    }
    p[32] = lrun;
  }
  __syncthreads();
  if (kh == 0) {
    float* p = scr + (size_t)(qh * 64 + lane) * 33;
#pragma unroll
    for (int i = 0; i < 16; ++i) {
      oacc0[i] += p[i];
      oacc1[i] += p[16 + i];
    }
    lrun += p[32];
    float linv = 1.0f / lrun;
#pragma unroll
    for (int r = 0; r < 16; ++r) {
      int qrow = (r & 3) + 8 * (r >> 2) + 4 * hi;
      float lf = __shfl(linv, qrow, 64);
      int grow = b * 2048 + q0 + qrow;
      int colb = h * 64 + ln31;
      Xh[(size_t)grow * 768 + colb] = f32_to_bf16(oacc0[r] * lf);
      Xh[(size_t)grow * 768 + colb + 32] = f32_to_bf16(oacc1[r] * lf);
    }
  }
}

// ---------------- launch ----------------
extern "C" void kernel_launch(void* const* d_in, const int* in_sizes, int n_in,
                              void* d_out, int out_size, void* d_ws, size_t ws_size,
                              hipStream_t stream) {
  const float* x = (const float*)d_in[0];      // [2,2048,768]
  const float* W_qkv = (const float*)d_in[1];  // [768,2304]
  const float* b_qkv = (const float*)d_in[2];  // [2304]
  const float* W_out = (const float*)d_in[3];  // [768,768]
  const float* b_out = (const float*)d_in[4];  // [768]
  float* out = (float*)d_out;                  // [4096,768]
  char* ws = (char*)d_ws;

  unsigned short* Xh = (unsigned short*)(ws + 0);           // 4096x768 bf16 (attn out H)
  unsigned short* Xb = (unsigned short*)(ws + 18874368);    // 4096x768 bf16 (x cast)
  unsigned short* Wq_t = (unsigned short*)(ws + 25165824);  // 2304x768 bf16
  unsigned short* Wo_t = (unsigned short*)(ws + 28704768);  // 768x768 bf16
  unsigned short* Qb = (unsigned short*)(ws + 32243712);    // 24x2048x64 (pre-scaled)
  unsigned short* Kb = (unsigned short*)(ws + 38535168);    // 24x2048x64
  unsigned short* Vt = (unsigned short*)(ws + 51118080);    // 24x64x2048

  k_prep<<<3840, 256, 0, stream>>>(x, W_qkv, W_out, Xb, Wq_t, Wo_t);
  k_gemm_qkv<<<dim3(32, 36), 256, 0, stream>>>(Xb, Wq_t, b_qkv, 4096, 2304, 768, Qb, Kb, Vt);
  k_attn<<<dim3(24, 32), 256, 0, stream>>>(Qb, Kb, Vt, Xh);
  k_gemm2<<<dim3(64, 12), 256, 0, stream>>>(Xh, Wo_t, b_out, out, 4096, 768, 768);
}